// Round 10
// baseline (102.709 us; speedup 1.0000x reference)
//
#include <hip/hip_runtime.h>

// AllPoleDigitalFilter via overlap-and-discard.
// Numerics validated R8: frame-aligned start nb=(ci-8)>>1 (warm 320..360),
// exact per-sample gain, per-8-group midpoint taps -> absmax 0.0352
// (threshold 0.1056).
// R9 theory (divergent x loads -> ~1300 stall cyc/group, unhidable at 0.78
// waves/SIMD) still stands; R9 FAILED on a pipeline off-by-one: rotation
// moved to group START so f=0,gg=0 consumed group 1's x (ci<8 threads have
// no warm-up -> absmax 4.28). R10: load next group into temps at group
// start, consume current, rotate at group END (R8 discipline).

typedef float v2f __attribute__((ext_vector_type(2)));

#define BATCH 32
#define N_FRAMES 800
#define D_COEF 25
#define P_FRAME 80
#define T_SAMP 64000
#define LCH 40
#define CHUNKS 1600              // per batch row
#define XFR 40                   // x frames staged per block
#define XSTRIDE 84               // 80 data + 4 pad floats (bank spread)
#define CFR 41                   // coeff rows staged (need n and n+1)
#define CSTRIDE 26               // 25 data + 1 pad (even -> b64-aligned)
#define XF4 (XFR * 20)           // 800 float4s of x data per block

__global__
__attribute__((amdgpu_flat_work_group_size(64, 64)))
__attribute__((amdgpu_waves_per_eu(1, 1)))
void lpc_kernel(const float* __restrict__ x,
                const float* __restrict__ a,
                float* __restrict__ out) {
    __shared__ float lds[XFR * XSTRIDE + CFR * CSTRIDE];   // 17,704 B
    float* xl = lds;
    float* cl = lds + XFR * XSTRIDE;

    const int tid = threadIdx.x;
    const int B = blockIdx.x;
    const int b = B / 25;                    // 25 blocks per batch row
    const int C0 = (B - b * 25) * 64;        // first chunk of this block

    const float* xrow = x + (size_t)b * T_SAMP;
    float* orow = out + (size_t)b * T_SAMP;
    const float* arow = a + (size_t)b * (N_FRAMES * D_COEF);

    int nb0 = (C0 - 8) >> 1; if (nb0 < 0) nb0 = 0;   // block's first frame
    const int t_base = nb0 * P_FRAME;

    // ---- coalesced staging: x (800 float4s, frame-padded layout) ----
    for (int i = tid; i < XF4; i += 64) {
        int fr = i / 20;
        int wi = i - fr * 20;
        int gx = t_base + 4 * i;
        if (gx > T_SAMP - 4) gx = T_SAMP - 4;        // legal; garbage unused
        *(float4*)(xl + fr * XSTRIDE + 4 * wi) = *(const float4*)(xrow + gx);
    }
    // ---- coalesced staging: coeff rows nb0 .. nb0+40 ----
    for (int i = tid; i < CFR * D_COEF; i += 64) {
        int r = i / D_COEF;
        int d = i - r * D_COEF;
        int n = nb0 + r; if (n > N_FRAMES - 1) n = N_FRAMES - 1;
        cl[r * CSTRIDE + d] = arow[n * D_COEF + d];
    }
    __syncthreads();

    // ---- per-thread recurrence: 5 frames x 10 groups x 8 samples ----
    const int ci = C0 + tid;
    const int s0 = ci * LCH;
    int nb = (ci - 8) >> 1; if (nb < 0) nb = 0;
    const int fx = nb - nb0;                 // first frame row (0..31)
    const int t0 = nb * P_FRAME;

    float w[40];
#pragma unroll
    for (int i = 0; i < 40; ++i) w[i] = 0.0f;
#define WR(i) w[(i) % 40]

    // x pipeline: xc = current group; loaded fresh each group, rotated at END
    float4 xc0, xc1;
    {
        const float* p = xl + fx * XSTRIDE;
        xc0 = *(const float4*)(p);
        xc1 = *(const float4*)(p + 4);
    }

    const float inv_p = 1.0f / (float)P_FRAME;

#pragma unroll 1
    for (int f = 0; f < 5; ++f) {
        const float* r0 = cl + (fx + f) * CSTRIDE;
        const float* r1 = r0 + CSTRIDE;

        // gain: exact per-sample; taps: group-0 midpoint, stepped 8/group
        float k, dk;
        {
            float2 g0 = *(const float2*)(r0);
            float2 g1 = *(const float2*)(r1);
            dk = (g1.x - g0.x) * inv_p;
            k = g0.x;
        }
        v2f cp[12], dp[12];
#pragma unroll
        for (int r = 0; r < 12; ++r) {
            float2 c0 = *(const float2*)(r0 + 1 + 2 * r);   // taps 2r+1, 2r+2
            float2 c1 = *(const float2*)(r1 + 1 + 2 * r);
            float ddx = (c1.x - c0.x) * inv_p;
            float ddy = (c1.y - c0.y) * inv_p;
            cp[r].x = fmaf(ddx, 3.5f, c0.x);
            cp[r].y = fmaf(ddy, 3.5f, c0.y);
            dp[r].x = 8.0f * ddx;
            dp[r].y = 8.0f * ddy;
        }
#define CT(m) ((m) & 1 ? cp[((m) - 1) >> 1].x : cp[((m) - 2) >> 1].y)

        const int tf = t0 + f * P_FRAME;
        const int xoff = (fx + f) * XSTRIDE;

#pragma unroll
        for (int gg = 0; gg < 10; ++gg) {
            const int tg = tf + gg * 8;
            // prefetch NEXT group into temps (consumed after rotation at end);
            // gg==9 -> next frame's group 0 (row fx+f+1; <= 36, staged)
            int noff = (gg == 9) ? xoff + XSTRIDE : xoff + (gg + 1) * 8;
            const float* pn = xl + noff;
            float4 xf0 = *(const float4*)(pn);
            float4 xf1 = *(const float4*)(pn + 4);

#pragma unroll
            for (int j = 0; j < 8; ++j) {
                const int P = 24 + gg * 8 + j;       // compile-time ring pos
                float xv = (j == 0) ? xc0.x : (j == 1) ? xc0.y
                         : (j == 2) ? xc0.z : (j == 3) ? xc0.w
                         : (j == 4) ? xc1.x : (j == 5) ? xc1.y
                         : (j == 6) ? xc1.z : xc1.w;
                float e = k * xv;
                float ch0 = fmaf(-CT(3), WR(P - 3), e);
                float ch1 = -CT(4) * WR(P - 4);
                float ch2 = -CT(5) * WR(P - 5);
                float ch3 = -CT(6) * WR(P - 6);
#pragma unroll
                for (int m = 7; m <= 24; ++m) {
                    if ((m & 3) == 3)      ch0 = fmaf(-CT(m), WR(P - m), ch0);
                    else if ((m & 3) == 0) ch1 = fmaf(-CT(m), WR(P - m), ch1);
                    else if ((m & 3) == 1) ch2 = fmaf(-CT(m), WR(P - m), ch2);
                    else                   ch3 = fmaf(-CT(m), WR(P - m), ch3);
                }
                float partial = (ch0 + ch1) + (ch2 + ch3);
                float u = fmaf(-CT(2), WR(P - 2), partial);
                float y = fmaf(-CT(1), WR(P - 1), u);
                WR(P) = y;
                k += dk;
            }

            if ((unsigned)(tg - s0) < 40u) {         // tg, s0 multiples of 8
                const int Q = 24 + gg * 8;
                *(float4*)(orow + tg)     = make_float4(WR(Q + 0), WR(Q + 1), WR(Q + 2), WR(Q + 3));
                *(float4*)(orow + tg + 4) = make_float4(WR(Q + 4), WR(Q + 5), WR(Q + 6), WR(Q + 7));
            }
            if (gg < 9) {
#pragma unroll
                for (int r = 0; r < 12; ++r) cp[r] += dp[r];   // v_pk_add_f32
            }
            xc0 = xf0; xc1 = xf1;                    // rotate at group END
        }
#undef CT
    }
#undef WR
}

extern "C" void kernel_launch(void* const* d_in, const int* in_sizes, int n_in,
                              void* d_out, int out_size, void* d_ws, size_t ws_size,
                              hipStream_t stream) {
    const float* x = (const float*)d_in[0];
    const float* a = (const float*)d_in[1];
    float* out = (float*)d_out;

    dim3 block(64);
    dim3 grid(BATCH * (CHUNKS / 64));    // 800 blocks, 1 wave each
    hipLaunchKernelGGL(lpc_kernel, grid, block, 0, stream, x, a, out);
}